// Round 6
// baseline (2831.987 us; speedup 1.0000x reference)
//
#include <hip/hip_runtime.h>

#define N_NODES   50000
#define N_EDGES   640000
#define DIM       128
#define N_LAYERS  5
#define N_GRAPHS  512
#define N_CLASSES 128
#define NB_SCAN   196   // ceil(N_NODES/256)

typedef __attribute__((ext_vector_type(8))) short short8;     // 8 bf16 (4 VGPRs)
typedef __attribute__((ext_vector_type(4))) float floatx4;    // MFMA acc

__device__ inline float bfhi(unsigned u) { return __uint_as_float(u & 0xffff0000u); }
__device__ inline float bflo(unsigned u) { return __uint_as_float(u << 16); }
__device__ inline unsigned f2bf(float f) {          // round-to-nearest-even
  unsigned x = __float_as_uint(f);
  return (x + 0x7fffu + ((x >> 16) & 1u)) >> 16;
}

// ---------------- zero-init scratch accumulators (ws is poisoned 0xAA) -----
__global__ void k_zero(int* __restrict__ deg, int* __restrict__ fill,
                       float* __restrict__ pool, int* __restrict__ cntI) {
  int i = blockIdx.x * 256 + threadIdx.x;
  if (i < N_NODES) { deg[i] = 0; fill[i] = 0; }
  if (i < N_GRAPHS * DIM) pool[i] = 0.f;
  if (i < N_GRAPHS) cntI[i] = 0;
}

// -------- degree histogram over dst + per-graph node counts ---------------
__global__ void k_deg(const int* __restrict__ dst, int* __restrict__ deg,
                      const int* __restrict__ batch, int* __restrict__ cntI) {
  int e = blockIdx.x * 256 + threadIdx.x;
  if (e < N_EDGES) atomicAdd(&deg[dst[e]], 1);
  if (e < N_NODES) atomicAdd(&cntI[batch[e]], 1);
}

// ---------------- exclusive scan deg -> row_ptr (3 phases) -----------------
__global__ void k_scan1(const int* __restrict__ deg, int* __restrict__ bsum) {
  __shared__ int s[256];
  int t = threadIdx.x, i = blockIdx.x * 256 + t;
  s[t] = (i < N_NODES) ? deg[i] : 0;
  __syncthreads();
  for (int o = 128; o > 0; o >>= 1) {
    if (t < o) s[t] += s[t + o];
    __syncthreads();
  }
  if (t == 0) bsum[blockIdx.x] = s[0];
}

__global__ void k_scan2(int* __restrict__ bsum) {
  __shared__ int s[256];
  int t = threadIdx.x;
  s[t] = (t < NB_SCAN) ? bsum[t] : 0;
  __syncthreads();
  for (int o = 1; o < 256; o <<= 1) {
    int add = (t >= o) ? s[t - o] : 0;
    __syncthreads();
    s[t] += add;
    __syncthreads();
  }
  int ex = (t == 0) ? 0 : s[t - 1];
  if (t < NB_SCAN) bsum[t] = ex;
}

__global__ void k_scan3(const int* __restrict__ deg, const int* __restrict__ bsum,
                        int* __restrict__ row_ptr) {
  __shared__ int s[256];
  int t = threadIdx.x, i = blockIdx.x * 256 + t;
  s[t] = (i < N_NODES) ? deg[i] : 0;
  __syncthreads();
  for (int o = 1; o < 256; o <<= 1) {
    int add = (t >= o) ? s[t - o] : 0;
    __syncthreads();
    s[t] += add;
    __syncthreads();
  }
  int ex = bsum[blockIdx.x] + ((t == 0) ? 0 : s[t - 1]);
  if (i < N_NODES) row_ptr[i] = ex;
  if (blockIdx.x == 0 && t == 0) row_ptr[N_NODES] = N_EDGES;
}

// ---------------- CSR fill: one 8B scatter per edge (src,eid packed) -------
__global__ void k_fill(const int* __restrict__ src, const int* __restrict__ dst,
                       const int* __restrict__ row_ptr, int* __restrict__ fill,
                       int2* __restrict__ col) {
  int e = blockIdx.x * 256 + threadIdx.x;
  if (e < N_EDGES) {
    int d = dst[e];
    int pos = row_ptr[d] + atomicAdd(&fill[d], 1);
    col[pos] = make_int2(src[e], e);
  }
}

// ------- weights bf16+transpose, plus v0 = emb @ Ws[0] in the last block ---
// v0 valid because x==0 for all nodes (vocab=1): h0 is rank-1, so layer 0
// collapses to ean @ We0 + (1+[deg>0]) * v0 + b0.
__global__ void k_wconv(const float* __restrict__ Ws, const float* __restrict__ Wes,
                        unsigned short* __restrict__ Wt_s, unsigned short* __restrict__ Wt_e,
                        const float* __restrict__ node_emb, float* __restrict__ v0) {
  if (blockIdx.x == 640) {               // v0 block
    int c = threadIdx.x;
    if (c < DIM) {
      float acc = 0.f;
      for (int k = 0; k < DIM; k++) acc += node_emb[k] * Ws[(size_t)k * DIM + c];
      v0[c] = acc;
    }
    return;
  }
  int idx = blockIdx.x * 256 + threadIdx.x;          // total 2*5*128*128 = 163840
  int which = idx / (N_LAYERS * DIM * DIM);
  int rem = idx - which * (N_LAYERS * DIM * DIM);
  int l = rem >> 14;            // /16384
  int c = (rem >> 7) & 127;
  int k = rem & 127;
  const float* W = which ? Wes : Ws;
  unsigned short* O = which ? Wt_e : Wt_s;
  float v = W[((size_t)l * DIM + k) * DIM + c];
  O[((size_t)l * DIM + c) * DIM + k] = (unsigned short)f2bf(v);
}

// -------- EAn = segsum(edge_attr,dst)/max(deg,1) (bf16); rdeg --------------
__global__ void k_ean_init(const int* __restrict__ row_ptr, const int2* __restrict__ col,
                           const float* __restrict__ edge_attr,
                           unsigned short* __restrict__ ean, float* __restrict__ rdeg) {
  int sub = threadIdx.x >> 5;
  int lane = threadIdx.x & 31;
  int i = blockIdx.x * 8 + sub;
  if (i >= N_NODES) return;
  int b = row_ptr[i], e = row_ptr[i + 1];
  float ax = 0.f, ay = 0.f, az = 0.f, aw = 0.f;
  int p = b;
  for (; p + 4 <= e; p += 4) {
    int e0 = col[p].y, e1 = col[p + 1].y, e2 = col[p + 2].y, e3 = col[p + 3].y;
    float4 v0 = ((const float4*)(edge_attr + (size_t)e0 * DIM))[lane];
    float4 v1 = ((const float4*)(edge_attr + (size_t)e1 * DIM))[lane];
    float4 v2 = ((const float4*)(edge_attr + (size_t)e2 * DIM))[lane];
    float4 v3 = ((const float4*)(edge_attr + (size_t)e3 * DIM))[lane];
    ax += v0.x + v1.x + v2.x + v3.x;
    ay += v0.y + v1.y + v2.y + v3.y;
    az += v0.z + v1.z + v2.z + v3.z;
    aw += v0.w + v1.w + v2.w + v3.w;
  }
  for (; p < e; p++) {
    int e0 = col[p].y;
    float4 v0 = ((const float4*)(edge_attr + (size_t)e0 * DIM))[lane];
    ax += v0.x; ay += v0.y; az += v0.z; aw += v0.w;
  }
  float r = 1.0f / (float)max(e - b, 1);
  if (lane == 0) rdeg[i] = r;
  uint2 o;
  o.x = f2bf(ax * r) | (f2bf(ay * r) << 16);
  o.y = f2bf(az * r) | (f2bf(aw * r) << 16);
  ((uint2*)(ean + (size_t)i * DIM))[lane] = o;
}

// ------- layer 0: h = relu(ean @ We0 + s_i * v0 + b0),  s_i = 1+[deg>0] ----
__global__ __launch_bounds__(256) void k_gemm0(
    const unsigned short* __restrict__ ean, const unsigned short* __restrict__ W1,
    const float* __restrict__ v0, const float* __restrict__ bias,
    const int* __restrict__ deg, unsigned short* __restrict__ hout) {
  __shared__ unsigned short sW[128][72];   // W chunk (64-k at a time)
  int tid = threadIdx.x;
  int wave = tid >> 6, lane = tid & 63;
  int quad = lane >> 4, l16 = lane & 15;
  int row0 = blockIdx.x * 64;
  int row_a = row0 + wave * 16 + l16;      // A-operand row for this lane
  floatx4 acc[8];
  #pragma unroll
  for (int ci = 0; ci < 8; ci++) acc[ci] = (floatx4){0.f, 0.f, 0.f, 0.f};

  for (int kc = 0; kc < 128; kc += 64) {
    __syncthreads();
    #pragma unroll
    for (int q = 0; q < 4; q++) {
      int s = tid + 256 * q;
      int r = s >> 3, seg = s & 7;
      *(uint4*)(&sW[r][seg * 8]) =
          *(const uint4*)(W1 + (size_t)r * DIM + kc + seg * 8);
    }
    __syncthreads();
    #pragma unroll
    for (int ks = 0; ks < 64; ks += 32) {
      short8 a = {0, 0, 0, 0, 0, 0, 0, 0};
      if (row_a < N_NODES)
        a = *(const short8*)(ean + (size_t)row_a * DIM + kc + ks + quad * 8);
      #pragma unroll
      for (int ci = 0; ci < 8; ci++) {
        short8 b = *(const short8*)(&sW[ci * 16 + l16][ks + quad * 8]);
        acc[ci] = __builtin_amdgcn_mfma_f32_16x16x32_bf16(a, b, acc[ci], 0, 0, 0);
      }
    }
  }
  #pragma unroll
  for (int ci = 0; ci < 8; ci++) {
    int col = ci * 16 + l16;
    float bv = bias[col];
    float vv = v0[col];
    #pragma unroll
    for (int r = 0; r < 4; r++) {
      int row = row0 + wave * 16 + quad * 4 + r;
      if (row < N_NODES) {
        float s = (deg[row] > 0) ? 2.f : 1.f;
        float v = acc[ci][r] + bv + s * vv;
        v = fmaxf(v, 0.f);                       // layer 0 always has relu
        hout[(size_t)row * DIM + col] = (unsigned short)f2bf(v);
      }
    }
  }
}

// ------- layers 1..4:  h' = maybe_relu(u @ W0 + ean @ W1 + b) --------------
// u = hin + (A hin)/max(deg,1).  EDGE-PARALLEL gather: the block's CSR edge
// range is contiguous; 16 lane-groups split it evenly (load-balanced), find
// the destination row by 6-step binary search in an LDS row_ptr tile, and
// accumulate into fp32 LDS accumulators via ds_add_f32.  A-fragments for u
// are built on the fly from sAcc + hin + rdeg (no sU staging buffer).
// relu==0 (last layer): epilogue atomically accumulates into pool instead of
// writing hout (mean-pool fusion; h never round-trips to HBM).
__global__ __launch_bounds__(256) void k_layer(
    const int* __restrict__ row_ptr, const int2* __restrict__ col,
    const unsigned short* __restrict__ hin, const float* __restrict__ rdeg,
    const unsigned short* __restrict__ ean,
    const unsigned short* __restrict__ W0, const unsigned short* __restrict__ W1,
    const float* __restrict__ bias, unsigned short* __restrict__ hout,
    const int* __restrict__ batch, float* __restrict__ pool, int relu) {
  __shared__ float sAcc[64][132];          // 33.8KB fp32 accumulators (+4 pad)
  __shared__ unsigned short sW[128][72];   // 18.4KB W chunk (64-k at a time)
  __shared__ int srp[65];                  // row_ptr tile
  __shared__ int sbatch[64];
  int tid = threadIdx.x;
  int row0 = blockIdx.x * 64;

  // stage first W chunk (W0, kc=0) early — hides under the gather
  #pragma unroll
  for (int q = 0; q < 4; q++) {
    int s = tid + 256 * q;
    int r = s >> 3, seg = s & 7;
    *(uint4*)(&sW[r][seg * 8]) = *(const uint4*)(W0 + (size_t)r * DIM + seg * 8);
  }
  for (int z = tid; z < 64 * 132; z += 256) ((float*)sAcc)[z] = 0.f;
  if (tid <= 64) srp[tid] = row_ptr[min(row0 + tid, N_NODES)];
  if (tid < 64) sbatch[tid] = (row0 + tid < N_NODES) ? batch[row0 + tid] : 0;
  __syncthreads();

  // ---- edge-parallel gather
  {
    int g = tid >> 4, glane = tid & 15;
    int base = srp[0], end = srp[64];
    for (int p = base + g; p < end; p += 16) {
      int s = col[p].x;
      int i = 0;
      #pragma unroll
      for (int st = 32; st >= 1; st >>= 1)
        if (srp[i + st] <= p) i += st;
      uint4 hv = *(const uint4*)(hin + (size_t)s * DIM + glane * 8);
      float* a = &sAcc[i][glane * 8];
      atomicAdd(&a[0], bflo(hv.x)); atomicAdd(&a[1], bfhi(hv.x));
      atomicAdd(&a[2], bflo(hv.y)); atomicAdd(&a[3], bfhi(hv.y));
      atomicAdd(&a[4], bflo(hv.z)); atomicAdd(&a[5], bfhi(hv.z));
      atomicAdd(&a[6], bflo(hv.w)); atomicAdd(&a[7], bfhi(hv.w));
    }
  }
  __syncthreads();

  // ---- GEMM: acc = u @ W0 + ean(global) @ W1
  int wave = tid >> 6, lane = tid & 63;
  int quad = lane >> 4, l16 = lane & 15;
  int ra = wave * 16 + l16;                // A row within tile
  int row_a = row0 + ra;                   // global A row
  float rr = (row_a < N_NODES) ? rdeg[row_a] : 0.f;
  floatx4 acc[8];
  #pragma unroll
  for (int ci = 0; ci < 8; ci++) acc[ci] = (floatx4){0.f, 0.f, 0.f, 0.f};

  auto build_u = [&](int cb) -> short8 {   // cb = global k column base
    short8 a = {0, 0, 0, 0, 0, 0, 0, 0};
    if (row_a < N_NODES) {
      uint4 hv = *(const uint4*)(hin + (size_t)row_a * DIM + cb);
      const float* s = &sAcc[ra][cb];
      unsigned u0 = f2bf(bflo(hv.x) + s[0] * rr), u1 = f2bf(bfhi(hv.x) + s[1] * rr);
      unsigned u2 = f2bf(bflo(hv.y) + s[2] * rr), u3 = f2bf(bfhi(hv.y) + s[3] * rr);
      unsigned u4 = f2bf(bflo(hv.z) + s[4] * rr), u5 = f2bf(bfhi(hv.z) + s[5] * rr);
      unsigned u6 = f2bf(bflo(hv.w) + s[6] * rr), u7 = f2bf(bfhi(hv.w) + s[7] * rr);
      a = (short8){(short)u0, (short)u1, (short)u2, (short)u3,
                   (short)u4, (short)u5, (short)u6, (short)u7};
    }
    return a;
  };
  auto stage = [&](const unsigned short* W, int kc) {
    #pragma unroll
    for (int q = 0; q < 4; q++) {
      int s = tid + 256 * q;
      int r = s >> 3, seg = s & 7;
      *(uint4*)(&sW[r][seg * 8]) = *(const uint4*)(W + (size_t)r * DIM + kc + seg * 8);
    }
  };
  auto mfma_chunk = [&](int m, int kc) {
    #pragma unroll
    for (int ks = 0; ks < 64; ks += 32) {
      int cb = kc + ks + quad * 8;
      short8 a;
      if (m == 0) {
        a = build_u(cb);
      } else {
        a = (short8){0, 0, 0, 0, 0, 0, 0, 0};
        if (row_a < N_NODES)
          a = *(const short8*)(ean + (size_t)row_a * DIM + cb);
      }
      #pragma unroll
      for (int ci = 0; ci < 8; ci++) {
        short8 b = *(const short8*)(&sW[ci * 16 + l16][ks + quad * 8]);
        acc[ci] = __builtin_amdgcn_mfma_f32_16x16x32_bf16(a, b, acc[ci], 0, 0, 0);
      }
    }
  };

  mfma_chunk(0, 0);                                    // sW pre-staged
  __syncthreads(); stage(W0, 64); __syncthreads(); mfma_chunk(0, 64);
  __syncthreads(); stage(W1, 0);  __syncthreads(); mfma_chunk(1, 0);
  __syncthreads(); stage(W1, 64); __syncthreads(); mfma_chunk(1, 64);

  // ---- epilogue
  #pragma unroll
  for (int ci = 0; ci < 8; ci++) {
    int col_ = ci * 16 + l16;
    float bv = bias[col_];
    #pragma unroll
    for (int r = 0; r < 4; r++) {
      int rt = wave * 16 + quad * 4 + r;
      int row = row0 + rt;
      if (row < N_NODES) {
        float v = acc[ci][r] + bv;
        if (relu) {
          v = fmaxf(v, 0.f);
          hout[(size_t)row * DIM + col_] = (unsigned short)f2bf(v);
        } else {
          atomicAdd(&pool[(size_t)sbatch[rt] * DIM + col_], v);   // fused pool
        }
      }
    }
  }
}

// ---------------- out = (pool/cnt) @ Wp + bp -------------------------------
__global__ void k_out(const float* __restrict__ pool, const int* __restrict__ cntI,
                      const float* __restrict__ Wp, const float* __restrict__ bp,
                      float* __restrict__ out) {
  __shared__ float sp[DIM];
  int g = blockIdx.x, t = threadIdx.x;
  sp[t] = pool[(size_t)g * DIM + t];
  __syncthreads();
  float r = 1.0f / fmaxf((float)cntI[g], 1.0f);
  float acc = 0.f;
  for (int k = 0; k < DIM; k++) acc += sp[k] * Wp[(size_t)k * N_CLASSES + t];
  out[(size_t)g * N_CLASSES + t] = acc * r + bp[t];
}

extern "C" void kernel_launch(void* const* d_in, const int* in_sizes, int n_in,
                              void* d_out, int out_size, void* d_ws, size_t ws_size,
                              hipStream_t stream) {
  (void)in_sizes; (void)n_in; (void)out_size; (void)ws_size;
  const int*   x          = (const int*)d_in[0];
  const int*   edge_index = (const int*)d_in[1];
  const float* edge_attr  = (const float*)d_in[2];
  const int*   batch      = (const int*)d_in[3];
  const float* node_emb   = (const float*)d_in[4];
  const float* Ws         = (const float*)d_in[5];
  const float* bsin       = (const float*)d_in[6];
  const float* Wes        = (const float*)d_in[7];
  const float* Wp         = (const float*)d_in[8];
  const float* bp         = (const float*)d_in[9];
  (void)x;
  float* out = (float*)d_out;
  const int* src = edge_index;
  const int* dst = edge_index + N_EDGES;

  char* p = (char*)d_ws;
  auto alloc = [&](size_t bytes) {
    void* q = (void*)p;
    p += (bytes + 255) & ~(size_t)255;
    return q;
  };
  unsigned short* h    = (unsigned short*)alloc((size_t)N_NODES * DIM * 2);
  unsigned short* h2   = (unsigned short*)alloc((size_t)N_NODES * DIM * 2);
  unsigned short* ean  = (unsigned short*)alloc((size_t)N_NODES * DIM * 2);
  unsigned short* Wt_s = (unsigned short*)alloc((size_t)N_LAYERS * DIM * DIM * 2);
  unsigned short* Wt_e = (unsigned short*)alloc((size_t)N_LAYERS * DIM * DIM * 2);
  int*   deg     = (int*)  alloc((size_t)N_NODES * 4);
  float* rdeg    = (float*)alloc((size_t)N_NODES * 4);
  int*   row_ptr = (int*)  alloc((size_t)(N_NODES + 64) * 4);
  int*   fill    = (int*)  alloc((size_t)N_NODES * 4);
  int2*  col     = (int2*) alloc((size_t)N_EDGES * 8);
  float* pool    = (float*)alloc((size_t)N_GRAPHS * DIM * 4);
  int*   cntI    = (int*)  alloc((size_t)N_GRAPHS * 4);
  int*   bsum    = (int*)  alloc(256 * 4);
  float* v0      = (float*)alloc(DIM * 4);

  k_zero<<<256, 256, 0, stream>>>(deg, fill, pool, cntI);
  k_deg<<<(N_EDGES + 255) / 256, 256, 0, stream>>>(dst, deg, batch, cntI);
  k_scan1<<<NB_SCAN, 256, 0, stream>>>(deg, bsum);
  k_scan2<<<1, 256, 0, stream>>>(bsum);
  k_scan3<<<NB_SCAN, 256, 0, stream>>>(deg, bsum, row_ptr);
  k_fill<<<(N_EDGES + 255) / 256, 256, 0, stream>>>(src, dst, row_ptr, fill, col);
  k_wconv<<<641, 256, 0, stream>>>(Ws, Wes, Wt_s, Wt_e, node_emb, v0);
  k_ean_init<<<(N_NODES + 7) / 8, 256, 0, stream>>>(row_ptr, col, edge_attr, ean, rdeg);

  // layer 0: rank-1 collapse (h0 rows all == emb); writes h
  k_gemm0<<<(N_NODES + 63) / 64, 256, 0, stream>>>(
      ean, Wt_e, v0, bsin, deg, h);
  // layers 1..4: edge-parallel gather + dual GEMM; last layer fuses pooling
  const unsigned short* hin = h;
  unsigned short* hout = h2;
  for (int l = 1; l < N_LAYERS; l++) {
    k_layer<<<(N_NODES + 63) / 64, 256, 0, stream>>>(
        row_ptr, col, hin, rdeg, ean,
        Wt_s + (size_t)l * DIM * DIM, Wt_e + (size_t)l * DIM * DIM,
        bsin + (size_t)l * DIM, hout, batch, pool, (l < N_LAYERS - 1) ? 1 : 0);
    const unsigned short* tmp = hout; hout = (unsigned short*)hin; hin = tmp;
  }
  k_out<<<N_GRAPHS, N_CLASSES, 0, stream>>>(pool, cntI, Wp, bp, out);
}